// Round 2
// baseline (657.135 us; speedup 1.0000x reference)
//
#include <hip/hip_runtime.h>
#include <hip/hip_bf16.h>

typedef short bf16x8 __attribute__((ext_vector_type(8)));
typedef float f32x4 __attribute__((ext_vector_type(4)));

constexpr int NN = 100000;           // nodes
constexpr int NE = 1600000;          // edges
constexpr int HH = 128;              // hidden
constexpr int NR = 8;                // relations
constexpr int NBIN = 782;            // ceil(NN/128) bins by dst>>7
constexpr int CAPB = 6144;           // max edges per bin on the LDS fast path

__device__ __forceinline__ unsigned short f2bf(float f) {
    unsigned b = __float_as_uint(f);
    b += 0x7fffu + ((b >> 16) & 1u);       // round-to-nearest-even
    return (unsigned short)(b >> 16);
}

// ---- fused convert: blocks [0,1152): W transpose; rest: x ----
// Wt[L][s][f][d] (bf16) from fp32 W[d][f]; xb32[n][l] = pack(x[n][2l], x[n][2l+1])
__global__ void convertWX(const float* __restrict__ Wr0, const float* __restrict__ Wq0,
                          const float* __restrict__ Wr1, const float* __restrict__ Wq1,
                          unsigned short* __restrict__ Wt,
                          const int* __restrict__ node_idx,
                          const float* __restrict__ emb,
                          unsigned* __restrict__ xb32) {
    if (blockIdx.x < 1152) {           // 1152*256 = 294912 = 2*9*128*128
        int o = blockIdx.x * 256 + threadIdx.x;
        int L = o / 147456;
        int rem = o - L * 147456;
        int s = rem >> 14;
        int p = rem & 16383;
        int f = p >> 7;
        int d = p & 127;
        const float* Wq = L ? Wq1 : Wq0;
        const float* Wr = L ? Wr1 : Wr0;
        float v = (s == 0) ? Wq[d * 128 + f] : Wr[((s - 1) * 128 + d) * 128 + f];
        Wt[o] = f2bf(v);
    } else {
        int i = (blockIdx.x - 1152) * 256 + threadIdx.x;
        if (i >= NN * 64) return;
        int n = i >> 6, dp = i & 63;
        int row = node_idx[n];
        float2 v = *((const float2*)(emb + (size_t)row * HH) + dp);
        xb32[(size_t)n * 64 + dp] = (unsigned)f2bf(v.x) | ((unsigned)f2bf(v.y) << 16);
    }
}

// ---- pass A1: per-bin edge counts (LDS histogram -> global merge) ----
__global__ __launch_bounds__(256) void binCount(const int* __restrict__ edst,
                                                unsigned* __restrict__ binCounts) {
    __shared__ unsigned hist[NBIN];
    for (int i = threadIdx.x; i < NBIN; i += 256) hist[i] = 0;
    __syncthreads();
    int stride = gridDim.x * 256;
    for (int e = blockIdx.x * 256 + threadIdx.x; e < NE; e += stride)
        atomicAdd(&hist[((unsigned)edst[e]) >> 7], 1u);
    __syncthreads();
    for (int i = threadIdx.x; i < NBIN; i += 256)
        if (hist[i]) atomicAdd(&binCounts[i], hist[i]);
}

// ---- pass A2: exclusive scan of 782 bin counts; init cursors ----
__global__ void binScan(const unsigned* __restrict__ binCounts,
                        unsigned* __restrict__ binStarts,
                        unsigned* __restrict__ binCursor) {
    __shared__ unsigned sh[1024];
    int tid = threadIdx.x;
    unsigned v = (tid < NBIN) ? binCounts[tid] : 0u;
    sh[tid] = v;
    __syncthreads();
    for (int ofs = 1; ofs < 1024; ofs <<= 1) {
        unsigned t = (tid >= ofs) ? sh[tid - ofs] : 0u;
        __syncthreads();
        sh[tid] += t;
        __syncthreads();
    }
    if (tid < NBIN) {
        unsigned s = sh[tid] - v;
        binStarts[tid] = s;
        binCursor[tid] = s;
    }
    if (tid == 0) binStarts[NBIN] = NE;
}

// ---- pass A3: scatter edges into bins (block-chunked -> L2-local writes) ----
// payload: src(17b) | rel(3b)<<17 | dstlow(7b)<<20
__global__ __launch_bounds__(256) void binScatter(
        const int* __restrict__ esrc, const int* __restrict__ edst,
        const int* __restrict__ etype, unsigned* __restrict__ binCursor,
        unsigned* __restrict__ binned) {
    __shared__ unsigned hist[NBIN];
    __shared__ unsigned cur[NBIN];
    for (int i = threadIdx.x; i < NBIN; i += 256) hist[i] = 0;
    __syncthreads();
    int per = (NE + gridDim.x - 1) / gridDim.x;
    int lo = blockIdx.x * per;
    int hi = lo + per; if (hi > NE) hi = NE;
    for (int e = lo + threadIdx.x; e < hi; e += 256)
        atomicAdd(&hist[((unsigned)edst[e]) >> 7], 1u);
    __syncthreads();
    for (int i = threadIdx.x; i < NBIN; i += 256) {
        unsigned c = hist[i];
        cur[i] = c ? atomicAdd(&binCursor[i], c) : 0u;
    }
    __syncthreads();
    for (int e = lo + threadIdx.x; e < hi; e += 256) {
        unsigned d = (unsigned)edst[e];
        unsigned b = d >> 7;
        unsigned pos = atomicAdd(&cur[b], 1u);
        binned[pos] = (unsigned)esrc[e] | (((unsigned)etype[e]) << 17) |
                      ((d & 127u) << 20);
    }
}

// ---- pass B: per-bin LDS sort by (dstlow,rel); emit payload + CSR starts ----
// payload: yrow(20b) = src*8+rel  |  deg(12b)<<20  (deg = segment length)
__global__ __launch_bounds__(256) void binSort(
        const unsigned* __restrict__ binStarts, const unsigned* __restrict__ binned,
        unsigned* __restrict__ epk, unsigned* __restrict__ starts) {
    __shared__ unsigned hist[1024];
    __shared__ unsigned scn[1024];
    __shared__ unsigned cnts[1024];
    __shared__ unsigned part[256];
    __shared__ unsigned buf[CAPB];
    __shared__ unsigned outb[CAPB];
    int bin = blockIdx.x;
    int tid = threadIdx.x;
    unsigned base = binStarts[bin];
    int cnt = (int)(binStarts[bin + 1] - base);

    for (int i = tid; i < 1024; i += 256) hist[i] = 0;
    __syncthreads();
    for (int i = tid; i < cnt; i += 256) {
        unsigned p = binned[base + i];
        if (i < CAPB) buf[i] = p;
        atomicAdd(&hist[(p >> 17) & 0x3ffu], 1u);   // key = dstlow*8 + rel
    }
    __syncthreads();
    // exclusive scan of hist[1024]
    unsigned h4[4], tsum = 0;
#pragma unroll
    for (int j = 0; j < 4; ++j) { h4[j] = hist[tid * 4 + j]; tsum += h4[j]; }
    part[tid] = tsum;
    __syncthreads();
    for (int ofs = 1; ofs < 256; ofs <<= 1) {
        unsigned t = (tid >= ofs) ? part[tid - ofs] : 0u;
        __syncthreads();
        part[tid] += t;
        __syncthreads();
    }
    unsigned run = part[tid] - tsum;
#pragma unroll
    for (int j = 0; j < 4; ++j) { scn[tid * 4 + j] = run; run += h4[j]; }
    __syncthreads();
    // global CSR starts (starts[node*8+rel] == base + scn[key]); keep counts
    for (int i = tid; i < 1024; i += 256) {
        starts[(size_t)bin * 1024 + i] = base + scn[i];
        cnts[i] = hist[i];                           // segment length for deg
        hist[i] = scn[i];                            // reuse hist as cursor
    }
    __syncthreads();
    if (cnt <= CAPB) {
        for (int i = tid; i < cnt; i += 256) {
            unsigned p = buf[i];
            unsigned key = (p >> 17) & 0x3ffu;
            unsigned pos = atomicAdd(&hist[key], 1u);
            unsigned deg = cnts[key]; if (deg > 4095u) deg = 4095u;
            outb[pos] = ((p & 0x1ffffu) << 3) | (key & 7u) | (deg << 20);
        }
        __syncthreads();
        for (int i = tid; i < cnt; i += 256) epk[base + i] = outb[i];
    } else {                                          // never expected; safety
        for (int i = tid; i < cnt; i += 256) {
            unsigned p = binned[base + i];
            unsigned key = (p >> 17) & 0x3ffu;
            unsigned pos = atomicAdd(&hist[key], 1u);
            unsigned deg = cnts[key]; if (deg > 4095u) deg = 4095u;
            epk[base + pos] = ((p & 0x1ffffu) << 3) | (key & 7u) | (deg << 20);
        }
    }
}

// ---- transform-first GEMM, LDS-FREE: y[n][r] = x[n] @ W_r, root = x @ W_root
// A (x rows) hoisted to 32 VGPRs once (reused across all 9 s); B (Wt, 288 KB,
// L2-resident) fragments loaded straight from global each s. No LDS, one
// barrier total (x aliases root32: all A reads must precede any store).
__global__ __launch_bounds__(256, 3) void bigGemm(const unsigned short* x,
                                                  const unsigned short* __restrict__ Wt,
                                                  unsigned* __restrict__ y32,
                                                  unsigned* root32) {
    int tid = threadIdx.x;
    int wid = tid >> 6, lane = tid & 63;
    int quad = lane >> 4, l16 = lane & 15;
    int wr = wid >> 1, wc = wid & 1;   // wr: node half (32), wc: channel half (64)
    int m0 = blockIdx.x * 64;

    // A fragments: node = m0 + wr*32 + nt*16 + l16, k = kt*32 + quad*8
    bf16x8 ax[2][4];
#pragma unroll
    for (int nt = 0; nt < 2; ++nt) {
        int node = m0 + wr * 32 + nt * 16 + l16;
        node = node < NN ? node : NN - 1;
        const unsigned short* rp = x + (size_t)node * HH + quad * 8;
#pragma unroll
        for (int kt = 0; kt < 4; ++kt)
            ax[nt][kt] = *(const bf16x8*)(rp + kt * 32);
    }
    __syncthreads();   // drain A loads before any epilogue store (x==root32 alias)

    for (int s = 0; s < 9; ++s) {
        // B fragments: row f = wc*64 + ft*16 + l16 of Wt[s], k = kt*32 + quad*8
        const unsigned short* Bb = Wt + s * 16384 + (wc * 64 + l16) * 128 + quad * 8;
        bf16x8 bw[4][4];
#pragma unroll
        for (int ft = 0; ft < 4; ++ft)
#pragma unroll
            for (int kt = 0; kt < 4; ++kt)
                bw[ft][kt] = *(const bf16x8*)(Bb + ft * (16 * 128) + kt * 32);

        f32x4 acc[2][4];
#pragma unroll
        for (int nt = 0; nt < 2; ++nt)
#pragma unroll
            for (int ft = 0; ft < 4; ++ft) acc[nt][ft] = (f32x4){0.f, 0.f, 0.f, 0.f};

#pragma unroll
        for (int kt = 0; kt < 4; ++kt)
#pragma unroll
            for (int nt = 0; nt < 2; ++nt)
#pragma unroll
                for (int ft = 0; ft < 4; ++ft)
                    acc[nt][ft] = __builtin_amdgcn_mfma_f32_16x16x32_bf16(
                        bw[ft][kt], ax[nt][kt], acc[nt][ft], 0, 0, 0);

        // epilogue: D[f=quad*4+rg (+16*ft +64*wc)][node=l16 (+16*nt +32*wr)]
#pragma unroll
        for (int nt = 0; nt < 2; ++nt) {
            int node = m0 + wr * 32 + nt * 16 + l16;
            if (node < NN) {
                unsigned* dst = (s == 0) ? (root32 + (size_t)node * 64)
                                         : (y32 + ((size_t)node * 8 + (s - 1)) * 64);
#pragma unroll
                for (int ft = 0; ft < 4; ++ft) {
                    int f0 = wc * 64 + ft * 16 + quad * 4;
                    unsigned d0, d1;
                    asm("v_cvt_pk_bf16_f32 %0, %1, %2"
                        : "=v"(d0) : "v"(acc[nt][ft][0]), "v"(acc[nt][ft][1]));
                    asm("v_cvt_pk_bf16_f32 %0, %1, %2"
                        : "=v"(d1) : "v"(acc[nt][ft][2]), "v"(acc[nt][ft][3]));
                    *(uint2*)(dst + (f0 >> 1)) = make_uint2(d0, d1);
                }
            }
        }
    }
}

// ---- relation-free scaled segment-sum: ONE accumulator pair per lane ----
// out[node] = relu(root[node] + b + sum_e nrm_e * y[row_e])   (wave per node)
__global__ __launch_bounds__(256) void scatterAgg(
        const unsigned* __restrict__ starts, const unsigned* __restrict__ epk,
        const unsigned* __restrict__ y32, const unsigned* root32,
        const float* __restrict__ bias,
        float* __restrict__ outF, unsigned* outB) {
    int node = blockIdx.x * 4 + (threadIdx.x >> 6);
    if (node >= NN) return;
    int lane = threadIdx.x & 63;

    unsigned s0 = starts[(size_t)node * 8];
    unsigned s1 = starts[(size_t)node * 8 + 8];
    int cnt = (int)__builtin_amdgcn_readfirstlane((int)(s1 - s0));

    float ax = 0.f, ay = 0.f;
    for (int c0 = 0; c0 < cnt; c0 += 64) {
        unsigned myE = s0 + (unsigned)c0 + (unsigned)lane;
        unsigned pk = (myE < s1) ? epk[myE] : 0u;
        float nrm = __builtin_amdgcn_rcpf((float)(pk >> 20));   // 1/deg (pad: unused)
        int cend = cnt - c0;
        if (cend > 64) cend = 64;
        for (int base = 0; base < cend; base += 8) {
            int m = cend - base;
            if (m > 8) m = 8;
            int bix = base << 2;
            unsigned pj[8], qj[8];
            float nj[8];
#pragma unroll
            for (int j = 0; j < 8; ++j) {
                pj[j] = (unsigned)__builtin_amdgcn_ds_bpermute(bix + (j << 2), (int)pk);
                nj[j] = __uint_as_float(
                    (unsigned)__builtin_amdgcn_ds_bpermute(bix + (j << 2),
                                                           __float_as_int(nrm)));
            }
#pragma unroll
            for (int j = 0; j < 8; ++j)
                if (j < m) qj[j] = y32[((pj[j] & 0xFFFFFu) << 6) + (unsigned)lane];
#pragma unroll
            for (int j = 0; j < 8; ++j) {
                if (j < m) {
                    float lo = __uint_as_float(qj[j] << 16);
                    float hi = __uint_as_float(qj[j] & 0xffff0000u);
                    ax += lo * nj[j];
                    ay += hi * nj[j];
                }
            }
        }
    }

    unsigned r = root32[(size_t)node * 64 + lane];
    float2 bv = ((const float2*)bias)[lane];
    float ox = ax + __uint_as_float(r << 16) + bv.x;
    float oy = ay + __uint_as_float(r & 0xffff0000u) + bv.y;
    ox = ox > 0.f ? ox : 0.f;
    oy = oy > 0.f ? oy : 0.f;
    if (outF) {
        *(float2*)(outF + (size_t)node * HH + lane * 2) = make_float2(ox, oy);
    } else {
        outB[(size_t)node * 64 + lane] =
            (unsigned)f2bf(ox) | ((unsigned)f2bf(oy) << 16);
    }
}

extern "C" void kernel_launch(void* const* d_in, const int* in_sizes, int n_in,
                              void* d_out, int out_size, void* d_ws, size_t ws_size,
                              hipStream_t stream) {
    const int* node_idx = (const int*)d_in[0];
    const int* eidx     = (const int*)d_in[1];
    const int* etype    = (const int*)d_in[2];
    const float* emb    = (const float*)d_in[3];
    const float* Wr0    = (const float*)d_in[4];
    const float* Wq0    = (const float*)d_in[5];
    const float* b0     = (const float*)d_in[6];
    const float* Wr1    = (const float*)d_in[7];
    const float* Wq1    = (const float*)d_in[8];
    const float* b1     = (const float*)d_in[9];
    const int* esrc = eidx;
    const int* edst = eidx + NE;

    char* ws = (char*)d_ws;
    size_t off = 0;
    auto alloc = [&](size_t bytes) -> void* {
        void* p = ws + off;
        off = (off + bytes + 255) & ~(size_t)255;
        return p;
    };
    // Workspace ~240.6 MB (same proven layout; y32 reuses h32's slab).
    unsigned* binCounts = (unsigned*)alloc((size_t)NBIN * 4);
    unsigned* binStarts = (unsigned*)alloc((size_t)(NBIN + 1) * 4);
    unsigned* binCursor = (unsigned*)alloc((size_t)NBIN * 4);
    unsigned* starts    = (unsigned*)alloc((size_t)NBIN * 1024 * 4);   // 3.2 MB CSR
    unsigned* epk       = (unsigned*)alloc((size_t)NE * 4);
    unsigned* xb32      = (unsigned*)alloc((size_t)NN * 64 * 4);       // x / root / out
    unsigned* y32       = (unsigned*)alloc((size_t)NN * 8 * 64 * 4);   // 204.8 MB
    unsigned short* Wt  = (unsigned short*)alloc((size_t)2 * 9 * 16384 * 2);
    unsigned* binned = y32;   // alias: y32 dead until bigGemm, binned dead after binSort
    (void)ws_size; (void)n_in; (void)in_sizes; (void)out_size;

    hipMemsetAsync(binCounts, 0, (size_t)NBIN * 4, stream);
    convertWX<<<1152 + (NN * 64 + 255) / 256, 256, 0, stream>>>(
        Wr0, Wq0, Wr1, Wq1, Wt, node_idx, emb, xb32);
    binCount<<<256, 256, 0, stream>>>(edst, binCounts);
    binScan<<<1, 1024, 0, stream>>>(binCounts, binStarts, binCursor);
    binScatter<<<128, 256, 0, stream>>>(esrc, edst, etype, binCursor, binned);
    binSort<<<NBIN, 256, 0, stream>>>(binStarts, binned, epk, starts);

    int nblk = (NN + 63) / 64;
    // layer 0: y = x@W_r, root = x@W_root (in place), then scaled segment-sum
    bigGemm<<<nblk, 256, 0, stream>>>((const unsigned short*)xb32, Wt, y32, xb32);
    scatterAgg<<<(NN + 3) / 4, 256, 0, stream>>>(starts, epk, y32, xb32, b0,
                                                 nullptr, xb32);
    // layer 1: same on relu output; final result fp32 to d_out
    bigGemm<<<nblk, 256, 0, stream>>>((const unsigned short*)xb32, Wt + 147456,
                                      y32, xb32);
    scatterAgg<<<(NN + 3) / 4, 256, 0, stream>>>(starts, epk, y32, xb32, b1,
                                                 (float*)d_out, nullptr);
}

// Round 3
// 543.321 us; speedup vs baseline: 1.2095x; 1.2095x over previous
//
#include <hip/hip_runtime.h>
#include <hip/hip_bf16.h>

typedef short bf16x8 __attribute__((ext_vector_type(8)));
typedef float f32x4 __attribute__((ext_vector_type(4)));

constexpr int NN = 100000;           // nodes
constexpr int NE = 1600000;          // edges
constexpr int HH = 128;              // hidden
constexpr int NR = 8;                // relations
constexpr int NBIN = 782;            // ceil(NN/128) bins by dst>>7
constexpr int CAPB = 6144;           // max edges per bin on the LDS fast path

__device__ __forceinline__ unsigned short f2bf(float f) {
    unsigned b = __float_as_uint(f);
    b += 0x7fffu + ((b >> 16) & 1u);       // round-to-nearest-even
    return (unsigned short)(b >> 16);
}

// ---- fused convert: blocks [0,1152): W transpose; rest: x ----
// Wt[L][s][f][·] (bf16) from fp32 W[d][f], stored CHUNK-SWIZZLED: within each
// 256B row, 16B chunk c lands at c ^ (f&7)  (bank-conflict-free ds_read_b128
// in bigGemm while keeping global_load_lds linear — both-sides swizzle).
__global__ void convertWX(const float* __restrict__ Wr0, const float* __restrict__ Wq0,
                          const float* __restrict__ Wr1, const float* __restrict__ Wq1,
                          unsigned short* __restrict__ Wt,
                          const int* __restrict__ node_idx,
                          const float* __restrict__ emb,
                          unsigned* __restrict__ xb32) {
    if (blockIdx.x < 1152) {           // 1152*256 = 294912 = 2*9*128*128
        int o = blockIdx.x * 256 + threadIdx.x;
        int L = o / 147456;
        int rem = o - L * 147456;
        int s = rem >> 14;
        int p = rem & 16383;
        int f = p >> 7;
        int d = p & 127;
        const float* Wq = L ? Wq1 : Wq0;
        const float* Wr = L ? Wr1 : Wr0;
        float v = (s == 0) ? Wq[d * 128 + f] : Wr[((s - 1) * 128 + d) * 128 + f];
        int cs = (d >> 3) ^ (f & 7);                     // swizzled 16B-chunk idx
        Wt[(o & ~127) | (cs << 3) | (d & 7)] = f2bf(v);
    } else {
        int i = (blockIdx.x - 1152) * 256 + threadIdx.x;
        if (i >= NN * 64) return;
        int n = i >> 6, dp = i & 63;
        int row = node_idx[n];
        float2 v = *((const float2*)(emb + (size_t)row * HH) + dp);
        xb32[(size_t)n * 64 + dp] = (unsigned)f2bf(v.x) | ((unsigned)f2bf(v.y) << 16);
    }
}

// ---- pass A1: per-bin edge counts (LDS histogram -> global merge) ----
__global__ __launch_bounds__(256) void binCount(const int* __restrict__ edst,
                                                unsigned* __restrict__ binCounts) {
    __shared__ unsigned hist[NBIN];
    for (int i = threadIdx.x; i < NBIN; i += 256) hist[i] = 0;
    __syncthreads();
    int stride = gridDim.x * 256;
    for (int e = blockIdx.x * 256 + threadIdx.x; e < NE; e += stride)
        atomicAdd(&hist[((unsigned)edst[e]) >> 7], 1u);
    __syncthreads();
    for (int i = threadIdx.x; i < NBIN; i += 256)
        if (hist[i]) atomicAdd(&binCounts[i], hist[i]);
}

// ---- pass A2: exclusive scan of 782 bin counts; init cursors ----
__global__ void binScan(const unsigned* __restrict__ binCounts,
                        unsigned* __restrict__ binStarts,
                        unsigned* __restrict__ binCursor) {
    __shared__ unsigned sh[1024];
    int tid = threadIdx.x;
    unsigned v = (tid < NBIN) ? binCounts[tid] : 0u;
    sh[tid] = v;
    __syncthreads();
    for (int ofs = 1; ofs < 1024; ofs <<= 1) {
        unsigned t = (tid >= ofs) ? sh[tid - ofs] : 0u;
        __syncthreads();
        sh[tid] += t;
        __syncthreads();
    }
    if (tid < NBIN) {
        unsigned s = sh[tid] - v;
        binStarts[tid] = s;
        binCursor[tid] = s;
    }
    if (tid == 0) binStarts[NBIN] = NE;
}

// ---- pass A3: scatter edges into bins (block-chunked -> L2-local writes) ----
// payload: src(17b) | rel(3b)<<17 | dstlow(7b)<<20
__global__ __launch_bounds__(256) void binScatter(
        const int* __restrict__ esrc, const int* __restrict__ edst,
        const int* __restrict__ etype, unsigned* __restrict__ binCursor,
        unsigned* __restrict__ binned) {
    __shared__ unsigned hist[NBIN];
    __shared__ unsigned cur[NBIN];
    for (int i = threadIdx.x; i < NBIN; i += 256) hist[i] = 0;
    __syncthreads();
    int per = (NE + gridDim.x - 1) / gridDim.x;
    int lo = blockIdx.x * per;
    int hi = lo + per; if (hi > NE) hi = NE;
    for (int e = lo + threadIdx.x; e < hi; e += 256)
        atomicAdd(&hist[((unsigned)edst[e]) >> 7], 1u);
    __syncthreads();
    for (int i = threadIdx.x; i < NBIN; i += 256) {
        unsigned c = hist[i];
        cur[i] = c ? atomicAdd(&binCursor[i], c) : 0u;
    }
    __syncthreads();
    for (int e = lo + threadIdx.x; e < hi; e += 256) {
        unsigned d = (unsigned)edst[e];
        unsigned b = d >> 7;
        unsigned pos = atomicAdd(&cur[b], 1u);
        binned[pos] = (unsigned)esrc[e] | (((unsigned)etype[e]) << 17) |
                      ((d & 127u) << 20);
    }
}

// ---- pass B: per-bin LDS sort by (dstlow,rel); emit payload + CSR starts ----
// payload: yrow(20b) = src*8+rel  |  deg(12b)<<20  (deg = segment length)
__global__ __launch_bounds__(256) void binSort(
        const unsigned* __restrict__ binStarts, const unsigned* __restrict__ binned,
        unsigned* __restrict__ epk, unsigned* __restrict__ starts) {
    __shared__ unsigned hist[1024];
    __shared__ unsigned scn[1024];
    __shared__ unsigned cnts[1024];
    __shared__ unsigned part[256];
    __shared__ unsigned buf[CAPB];
    __shared__ unsigned outb[CAPB];
    int bin = blockIdx.x;
    int tid = threadIdx.x;
    unsigned base = binStarts[bin];
    int cnt = (int)(binStarts[bin + 1] - base);

    for (int i = tid; i < 1024; i += 256) hist[i] = 0;
    __syncthreads();
    for (int i = tid; i < cnt; i += 256) {
        unsigned p = binned[base + i];
        if (i < CAPB) buf[i] = p;
        atomicAdd(&hist[(p >> 17) & 0x3ffu], 1u);   // key = dstlow*8 + rel
    }
    __syncthreads();
    // exclusive scan of hist[1024]
    unsigned h4[4], tsum = 0;
#pragma unroll
    for (int j = 0; j < 4; ++j) { h4[j] = hist[tid * 4 + j]; tsum += h4[j]; }
    part[tid] = tsum;
    __syncthreads();
    for (int ofs = 1; ofs < 256; ofs <<= 1) {
        unsigned t = (tid >= ofs) ? part[tid - ofs] : 0u;
        __syncthreads();
        part[tid] += t;
        __syncthreads();
    }
    unsigned run = part[tid] - tsum;
#pragma unroll
    for (int j = 0; j < 4; ++j) { scn[tid * 4 + j] = run; run += h4[j]; }
    __syncthreads();
    // global CSR starts (starts[node*8+rel] == base + scn[key]); keep counts
    for (int i = tid; i < 1024; i += 256) {
        starts[(size_t)bin * 1024 + i] = base + scn[i];
        cnts[i] = hist[i];                           // segment length for deg
        hist[i] = scn[i];                            // reuse hist as cursor
    }
    __syncthreads();
    if (cnt <= CAPB) {
        for (int i = tid; i < cnt; i += 256) {
            unsigned p = buf[i];
            unsigned key = (p >> 17) & 0x3ffu;
            unsigned pos = atomicAdd(&hist[key], 1u);
            unsigned deg = cnts[key]; if (deg > 4095u) deg = 4095u;
            outb[pos] = ((p & 0x1ffffu) << 3) | (key & 7u) | (deg << 20);
        }
        __syncthreads();
        for (int i = tid; i < cnt; i += 256) epk[base + i] = outb[i];
    } else {                                          // never expected; safety
        for (int i = tid; i < cnt; i += 256) {
            unsigned p = binned[base + i];
            unsigned key = (p >> 17) & 0x3ffu;
            unsigned pos = atomicAdd(&hist[key], 1u);
            unsigned deg = cnts[key]; if (deg > 4095u) deg = 4095u;
            epk[base + pos] = ((p & 0x1ffffu) << 3) | (key & 7u) | (deg << 20);
        }
    }
}

// ---- transform-first GEMM: y[n][r] = x[n] @ W_r, root = x @ W_root ----
// A (x rows) in 32 VGPRs (reused across all 9 s, proven round-2 layout).
// B (Wt) LDS double-buffered via global_load_lds w=16: tile s+1 in flight
// while tile s computes; ONE barrier per s. Wt is chunk-swizzled in memory
// so linear global_load_lds + XOR ds_read => 2-way banks (free).
// M=128 nodes/block, 512 threads. x aliases root32 (barrier after A-loads).
__global__ __launch_bounds__(512, 4) void bigGemm(const unsigned short* x,
                                                  const unsigned short* __restrict__ Wt,
                                                  unsigned* __restrict__ y32,
                                                  unsigned* root32) {
    typedef __attribute__((address_space(3))) unsigned lds_u32_t;
    typedef const __attribute__((address_space(1))) unsigned glb_u32_t;
    __shared__ __align__(16) unsigned short Bl[2][16384];   // 2 x 32 KB

    int tid = threadIdx.x;
    int wid = tid >> 6, lane = tid & 63;
    int quad = lane >> 4, l16 = lane & 15;
    int wr = wid >> 1, wc = wid & 1;   // wr: node quarter (32), wc: channel half (64)
    int m0 = blockIdx.x * 128;
    int sw = l16 & 7;                  // read-side chunk swizzle

    auto prefetch = [&](int s, int b) {
        const char* gs = (const char*)Wt + (size_t)s * 32768 + wid * 4096 + lane * 16;
        char* ls = (char*)&Bl[b][0] + wid * 4096;
#pragma unroll
        for (int j = 0; j < 4; ++j)
            __builtin_amdgcn_global_load_lds((glb_u32_t*)(const void*)(gs + j * 1024),
                                             (lds_u32_t*)(void*)(ls + j * 1024),
                                             16, 0, 0);
    };

    prefetch(0, 0);

    // A fragments: node = m0 + wr*32 + nt*16 + l16, k = kt*32 + quad*8
    bf16x8 ax[2][4];
#pragma unroll
    for (int nt = 0; nt < 2; ++nt) {
        int node = m0 + wr * 32 + nt * 16 + l16;
        node = node < NN ? node : NN - 1;
        const unsigned short* rp = x + (size_t)node * HH + quad * 8;
#pragma unroll
        for (int kt = 0; kt < 4; ++kt)
            ax[nt][kt] = *(const bf16x8*)(rp + kt * 32);
    }
    __syncthreads();   // drains A loads + prefetch(0); covers x==root32 alias

    for (int s = 0; s < 9; ++s) {
        if (s < 8) prefetch(s + 1, (s + 1) & 1);
        const char* Bb = (const char*)&Bl[s & 1][0];

        f32x4 acc[2][4];
#pragma unroll
        for (int nt = 0; nt < 2; ++nt)
#pragma unroll
            for (int ft = 0; ft < 4; ++ft) acc[nt][ft] = (f32x4){0.f, 0.f, 0.f, 0.f};

#pragma unroll
        for (int kt = 0; kt < 4; ++kt) {
            bf16x8 bw[4];
#pragma unroll
            for (int ft = 0; ft < 4; ++ft) {
                int f = wc * 64 + ft * 16 + l16;
                bw[ft] = *(const bf16x8*)(Bb + f * 256 +
                                          (((kt * 4 + quad) ^ sw) << 4));
            }
#pragma unroll
            for (int nt = 0; nt < 2; ++nt)
#pragma unroll
                for (int ft = 0; ft < 4; ++ft)
                    acc[nt][ft] = __builtin_amdgcn_mfma_f32_16x16x32_bf16(
                        bw[ft], ax[nt][kt], acc[nt][ft], 0, 0, 0);
        }

        // epilogue: D[f=quad*4+rg (+16*ft +64*wc)][node=l16 (+16*nt +32*wr)]
#pragma unroll
        for (int nt = 0; nt < 2; ++nt) {
            int node = m0 + wr * 32 + nt * 16 + l16;
            if (node < NN) {
                unsigned* dst = (s == 0) ? (root32 + (size_t)node * 64)
                                         : (y32 + ((size_t)node * 8 + (s - 1)) * 64);
#pragma unroll
                for (int ft = 0; ft < 4; ++ft) {
                    int f0 = wc * 64 + ft * 16 + quad * 4;
                    unsigned d0, d1;
                    asm("v_cvt_pk_bf16_f32 %0, %1, %2"
                        : "=v"(d0) : "v"(acc[nt][ft][0]), "v"(acc[nt][ft][1]));
                    asm("v_cvt_pk_bf16_f32 %0, %1, %2"
                        : "=v"(d1) : "v"(acc[nt][ft][2]), "v"(acc[nt][ft][3]));
                    *(uint2*)(dst + (f0 >> 1)) = make_uint2(d0, d1);
                }
            }
        }
        __syncthreads();   // all reads of Bl[s&1] done; prefetch(s+1) drained
    }
}

// ---- relation-free scaled segment-sum: ONE accumulator pair per lane ----
// out[node] = relu(root[node] + b + sum_e nrm_e * y[row_e])   (wave per node)
__global__ __launch_bounds__(256) void scatterAgg(
        const unsigned* __restrict__ starts, const unsigned* __restrict__ epk,
        const unsigned* __restrict__ y32, const unsigned* root32,
        const float* __restrict__ bias,
        float* __restrict__ outF, unsigned* outB) {
    int node = blockIdx.x * 4 + (threadIdx.x >> 6);
    if (node >= NN) return;
    int lane = threadIdx.x & 63;

    unsigned s0 = starts[(size_t)node * 8];
    unsigned s1 = starts[(size_t)node * 8 + 8];
    int cnt = (int)__builtin_amdgcn_readfirstlane((int)(s1 - s0));

    float ax = 0.f, ay = 0.f;
    for (int c0 = 0; c0 < cnt; c0 += 64) {
        unsigned myE = s0 + (unsigned)c0 + (unsigned)lane;
        unsigned pk = (myE < s1) ? epk[myE] : 0u;
        float nrm = __builtin_amdgcn_rcpf((float)(pk >> 20));   // 1/deg (pad: unused)
        int cend = cnt - c0;
        if (cend > 64) cend = 64;
        for (int base = 0; base < cend; base += 8) {
            int m = cend - base;
            if (m > 8) m = 8;
            int bix = base << 2;
            unsigned pj[8], qj[8];
            float nj[8];
#pragma unroll
            for (int j = 0; j < 8; ++j) {
                pj[j] = (unsigned)__builtin_amdgcn_ds_bpermute(bix + (j << 2), (int)pk);
                nj[j] = __uint_as_float(
                    (unsigned)__builtin_amdgcn_ds_bpermute(bix + (j << 2),
                                                           __float_as_int(nrm)));
            }
#pragma unroll
            for (int j = 0; j < 8; ++j)
                if (j < m) qj[j] = y32[((pj[j] & 0xFFFFFu) << 6) + (unsigned)lane];
#pragma unroll
            for (int j = 0; j < 8; ++j) {
                if (j < m) {
                    float lo = __uint_as_float(qj[j] << 16);
                    float hi = __uint_as_float(qj[j] & 0xffff0000u);
                    ax += lo * nj[j];
                    ay += hi * nj[j];
                }
            }
        }
    }

    unsigned r = root32[(size_t)node * 64 + lane];
    float2 bv = ((const float2*)bias)[lane];
    float ox = ax + __uint_as_float(r << 16) + bv.x;
    float oy = ay + __uint_as_float(r & 0xffff0000u) + bv.y;
    ox = ox > 0.f ? ox : 0.f;
    oy = oy > 0.f ? oy : 0.f;
    if (outF) {
        *(float2*)(outF + (size_t)node * HH + lane * 2) = make_float2(ox, oy);
    } else {
        outB[(size_t)node * 64 + lane] =
            (unsigned)f2bf(ox) | ((unsigned)f2bf(oy) << 16);
    }
}

extern "C" void kernel_launch(void* const* d_in, const int* in_sizes, int n_in,
                              void* d_out, int out_size, void* d_ws, size_t ws_size,
                              hipStream_t stream) {
    const int* node_idx = (const int*)d_in[0];
    const int* eidx     = (const int*)d_in[1];
    const int* etype    = (const int*)d_in[2];
    const float* emb    = (const float*)d_in[3];
    const float* Wr0    = (const float*)d_in[4];
    const float* Wq0    = (const float*)d_in[5];
    const float* b0     = (const float*)d_in[6];
    const float* Wr1    = (const float*)d_in[7];
    const float* Wq1    = (const float*)d_in[8];
    const float* b1     = (const float*)d_in[9];
    const int* esrc = eidx;
    const int* edst = eidx + NE;

    char* ws = (char*)d_ws;
    size_t off = 0;
    auto alloc = [&](size_t bytes) -> void* {
        void* p = ws + off;
        off = (off + bytes + 255) & ~(size_t)255;
        return p;
    };
    // Workspace ~240.6 MB (same proven layout; y32 reuses h32's slab).
    unsigned* binCounts = (unsigned*)alloc((size_t)NBIN * 4);
    unsigned* binStarts = (unsigned*)alloc((size_t)(NBIN + 1) * 4);
    unsigned* binCursor = (unsigned*)alloc((size_t)NBIN * 4);
    unsigned* starts    = (unsigned*)alloc((size_t)NBIN * 1024 * 4);   // 3.2 MB CSR
    unsigned* epk       = (unsigned*)alloc((size_t)NE * 4);
    unsigned* xb32      = (unsigned*)alloc((size_t)NN * 64 * 4);       // x / root / out
    unsigned* y32       = (unsigned*)alloc((size_t)NN * 8 * 64 * 4);   // 204.8 MB
    unsigned short* Wt  = (unsigned short*)alloc((size_t)2 * 9 * 16384 * 2);
    unsigned* binned = y32;   // alias: y32 dead until bigGemm, binned dead after binSort
    (void)ws_size; (void)n_in; (void)in_sizes; (void)out_size;

    hipMemsetAsync(binCounts, 0, (size_t)NBIN * 4, stream);
    convertWX<<<1152 + (NN * 64 + 255) / 256, 256, 0, stream>>>(
        Wr0, Wq0, Wr1, Wq1, Wt, node_idx, emb, xb32);
    binCount<<<256, 256, 0, stream>>>(edst, binCounts);
    binScan<<<1, 1024, 0, stream>>>(binCounts, binStarts, binCursor);
    binScatter<<<128, 256, 0, stream>>>(esrc, edst, etype, binCursor, binned);
    binSort<<<NBIN, 256, 0, stream>>>(binStarts, binned, epk, starts);

    int nblk = (NN + 127) / 128;
    // layer 0: y = x@W_r, root = x@W_root (in place), then scaled segment-sum
    bigGemm<<<nblk, 512, 0, stream>>>((const unsigned short*)xb32, Wt, y32, xb32);
    scatterAgg<<<(NN + 3) / 4, 256, 0, stream>>>(starts, epk, y32, xb32, b0,
                                                 nullptr, xb32);
    // layer 1: same on relu output; final result fp32 to d_out
    bigGemm<<<nblk, 512, 0, stream>>>((const unsigned short*)xb32, Wt + 147456,
                                      y32, xb32);
    scatterAgg<<<(NN + 3) / 4, 256, 0, stream>>>(starts, epk, y32, xb32, b1,
                                                 (float*)d_out, nullptr);
}

// Round 4
// 504.178 us; speedup vs baseline: 1.3034x; 1.0776x over previous
//
#include <hip/hip_runtime.h>
#include <hip/hip_bf16.h>

typedef short bf16x8 __attribute__((ext_vector_type(8)));
typedef float f32x4 __attribute__((ext_vector_type(4)));

constexpr int NN = 100000;           // nodes
constexpr int NE = 1600000;          // edges
constexpr int HH = 128;              // hidden
constexpr int NR = 8;                // relations
constexpr int NBIN = 782;            // ceil(NN/128) bins by dst>>7
constexpr int CAPB = 6144;           // max edges per bin on the LDS fast path

__device__ __forceinline__ unsigned short f2bf(float f) {
    unsigned b = __float_as_uint(f);
    b += 0x7fffu + ((b >> 16) & 1u);       // round-to-nearest-even
    return (unsigned short)(b >> 16);
}

// ---- fused convert: blocks [0,1152): W transpose; rest: x ----
// Wt[L][s][f][·] (bf16) from fp32 W[d][f], stored CHUNK-SWIZZLED: within each
// 256B row, 16B chunk c lands at c ^ (f&7)  (bank-conflict-free ds_read_b128
// in bigGemm while keeping global_load_lds linear — both-sides swizzle).
__global__ void convertWX(const float* __restrict__ Wr0, const float* __restrict__ Wq0,
                          const float* __restrict__ Wr1, const float* __restrict__ Wq1,
                          unsigned short* __restrict__ Wt,
                          const int* __restrict__ node_idx,
                          const float* __restrict__ emb,
                          unsigned* __restrict__ xb32) {
    if (blockIdx.x < 1152) {           // 1152*256 = 294912 = 2*9*128*128
        int o = blockIdx.x * 256 + threadIdx.x;
        int L = o / 147456;
        int rem = o - L * 147456;
        int s = rem >> 14;
        int p = rem & 16383;
        int f = p >> 7;
        int d = p & 127;
        const float* Wq = L ? Wq1 : Wq0;
        const float* Wr = L ? Wr1 : Wr0;
        float v = (s == 0) ? Wq[d * 128 + f] : Wr[((s - 1) * 128 + d) * 128 + f];
        int cs = (d >> 3) ^ (f & 7);                     // swizzled 16B-chunk idx
        Wt[(o & ~127) | (cs << 3) | (d & 7)] = f2bf(v);
    } else {
        int i = (blockIdx.x - 1152) * 256 + threadIdx.x;
        if (i >= NN * 64) return;
        int n = i >> 6, dp = i & 63;
        int row = node_idx[n];
        float2 v = *((const float2*)(emb + (size_t)row * HH) + dp);
        xb32[(size_t)n * 64 + dp] = (unsigned)f2bf(v.x) | ((unsigned)f2bf(v.y) << 16);
    }
}

// ---- pass A1: per-bin edge counts (LDS histogram -> global merge) ----
__global__ __launch_bounds__(256) void binCount(const int* __restrict__ edst,
                                                unsigned* __restrict__ binCounts) {
    __shared__ unsigned hist[NBIN];
    for (int i = threadIdx.x; i < NBIN; i += 256) hist[i] = 0;
    __syncthreads();
    int stride = gridDim.x * 256;
    for (int e = blockIdx.x * 256 + threadIdx.x; e < NE; e += stride)
        atomicAdd(&hist[((unsigned)edst[e]) >> 7], 1u);
    __syncthreads();
    for (int i = threadIdx.x; i < NBIN; i += 256)
        if (hist[i]) atomicAdd(&binCounts[i], hist[i]);
}

// ---- pass A2: exclusive scan of 782 bin counts; init cursors ----
__global__ void binScan(const unsigned* __restrict__ binCounts,
                        unsigned* __restrict__ binStarts,
                        unsigned* __restrict__ binCursor) {
    __shared__ unsigned sh[1024];
    int tid = threadIdx.x;
    unsigned v = (tid < NBIN) ? binCounts[tid] : 0u;
    sh[tid] = v;
    __syncthreads();
    for (int ofs = 1; ofs < 1024; ofs <<= 1) {
        unsigned t = (tid >= ofs) ? sh[tid - ofs] : 0u;
        __syncthreads();
        sh[tid] += t;
        __syncthreads();
    }
    if (tid < NBIN) {
        unsigned s = sh[tid] - v;
        binStarts[tid] = s;
        binCursor[tid] = s;
    }
    if (tid == 0) binStarts[NBIN] = NE;
}

// ---- pass A3: scatter edges into bins (block-chunked -> L2-local writes) ----
// payload: src(17b) | rel(3b)<<17 | dstlow(7b)<<20
__global__ __launch_bounds__(256) void binScatter(
        const int* __restrict__ esrc, const int* __restrict__ edst,
        const int* __restrict__ etype, unsigned* __restrict__ binCursor,
        unsigned* __restrict__ binned) {
    __shared__ unsigned hist[NBIN];
    __shared__ unsigned cur[NBIN];
    for (int i = threadIdx.x; i < NBIN; i += 256) hist[i] = 0;
    __syncthreads();
    int per = (NE + gridDim.x - 1) / gridDim.x;
    int lo = blockIdx.x * per;
    int hi = lo + per; if (hi > NE) hi = NE;
    for (int e = lo + threadIdx.x; e < hi; e += 256)
        atomicAdd(&hist[((unsigned)edst[e]) >> 7], 1u);
    __syncthreads();
    for (int i = threadIdx.x; i < NBIN; i += 256) {
        unsigned c = hist[i];
        cur[i] = c ? atomicAdd(&binCursor[i], c) : 0u;
    }
    __syncthreads();
    for (int e = lo + threadIdx.x; e < hi; e += 256) {
        unsigned d = (unsigned)edst[e];
        unsigned b = d >> 7;
        unsigned pos = atomicAdd(&cur[b], 1u);
        binned[pos] = (unsigned)esrc[e] | (((unsigned)etype[e]) << 17) |
                      ((d & 127u) << 20);
    }
}

// ---- pass B: per-bin LDS sort by (dstlow,rel); emit payload + CSR starts ----
// payload: yrow(20b) = src*8+rel  |  deg(12b)<<20  (deg = segment length)
__global__ __launch_bounds__(256) void binSort(
        const unsigned* __restrict__ binStarts, const unsigned* __restrict__ binned,
        unsigned* __restrict__ epk, unsigned* __restrict__ starts) {
    __shared__ unsigned hist[1024];
    __shared__ unsigned scn[1024];
    __shared__ unsigned cnts[1024];
    __shared__ unsigned part[256];
    __shared__ unsigned buf[CAPB];
    __shared__ unsigned outb[CAPB];
    int bin = blockIdx.x;
    int tid = threadIdx.x;
    unsigned base = binStarts[bin];
    int cnt = (int)(binStarts[bin + 1] - base);

    for (int i = tid; i < 1024; i += 256) hist[i] = 0;
    __syncthreads();
    for (int i = tid; i < cnt; i += 256) {
        unsigned p = binned[base + i];
        if (i < CAPB) buf[i] = p;
        atomicAdd(&hist[(p >> 17) & 0x3ffu], 1u);   // key = dstlow*8 + rel
    }
    __syncthreads();
    // exclusive scan of hist[1024]
    unsigned h4[4], tsum = 0;
#pragma unroll
    for (int j = 0; j < 4; ++j) { h4[j] = hist[tid * 4 + j]; tsum += h4[j]; }
    part[tid] = tsum;
    __syncthreads();
    for (int ofs = 1; ofs < 256; ofs <<= 1) {
        unsigned t = (tid >= ofs) ? part[tid - ofs] : 0u;
        __syncthreads();
        part[tid] += t;
        __syncthreads();
    }
    unsigned run = part[tid] - tsum;
#pragma unroll
    for (int j = 0; j < 4; ++j) { scn[tid * 4 + j] = run; run += h4[j]; }
    __syncthreads();
    // global CSR starts (starts[node*8+rel] == base + scn[key]); keep counts
    for (int i = tid; i < 1024; i += 256) {
        starts[(size_t)bin * 1024 + i] = base + scn[i];
        cnts[i] = hist[i];                           // segment length for deg
        hist[i] = scn[i];                            // reuse hist as cursor
    }
    __syncthreads();
    if (cnt <= CAPB) {
        for (int i = tid; i < cnt; i += 256) {
            unsigned p = buf[i];
            unsigned key = (p >> 17) & 0x3ffu;
            unsigned pos = atomicAdd(&hist[key], 1u);
            unsigned deg = cnts[key]; if (deg > 4095u) deg = 4095u;
            outb[pos] = ((p & 0x1ffffu) << 3) | (key & 7u) | (deg << 20);
        }
        __syncthreads();
        for (int i = tid; i < cnt; i += 256) epk[base + i] = outb[i];
    } else {                                          // never expected; safety
        for (int i = tid; i < cnt; i += 256) {
            unsigned p = binned[base + i];
            unsigned key = (p >> 17) & 0x3ffu;
            unsigned pos = atomicAdd(&hist[key], 1u);
            unsigned deg = cnts[key]; if (deg > 4095u) deg = 4095u;
            epk[base + pos] = ((p & 0x1ffffu) << 3) | (key & 7u) | (deg << 20);
        }
    }
}

// ---- transform-first GEMM: y[n][r] = x[n] @ W_r, root = x @ W_root ----
// A (x rows) in 32 VGPRs; B (Wt) LDS double-buffered via global_load_lds w=16.
// NEW: LDS-transpose epilogue — acc fragments land in a 64-row x 256B LDS tile
// (XOR-swizzled), then stored row-major as dwordx4 => 256B-granular y writes /
// 1KB-contiguous root writes (was 32B sectors). Two 64-row halves keep LDS at
// 80 KB -> 2 blocks/CU. x aliases root32 (all A reads precede first store).
__global__ __launch_bounds__(512, 4) void bigGemm(const unsigned short* x,
                                                  const unsigned short* __restrict__ Wt,
                                                  unsigned* __restrict__ y32,
                                                  unsigned* root32) {
    typedef __attribute__((address_space(3))) unsigned lds_u32_t;
    typedef const __attribute__((address_space(1))) unsigned glb_u32_t;
    __shared__ __align__(16) unsigned short Bl[2][16384];   // 64 KB W double-buf
    __shared__ __align__(16) unsigned Tld[64 * 64];         // 16 KB transpose buf

    int tid = threadIdx.x;
    int wid = tid >> 6, lane = tid & 63;
    int quad = lane >> 4, l16 = lane & 15;
    int wr = wid >> 1, wc = wid & 1;   // wr: node quarter (32), wc: channel half (64)
    int m0 = blockIdx.x * 128;
    int sw = l16 & 7;                  // read-side chunk swizzle for W

    auto prefetch = [&](int s, int b) {
        const char* gs = (const char*)Wt + (size_t)s * 32768 + wid * 4096 + lane * 16;
        char* ls = (char*)&Bl[b][0] + wid * 4096;
#pragma unroll
        for (int j = 0; j < 4; ++j)
            __builtin_amdgcn_global_load_lds((glb_u32_t*)(const void*)(gs + j * 1024),
                                             (lds_u32_t*)(void*)(ls + j * 1024),
                                             16, 0, 0);
    };

    prefetch(0, 0);

    // A fragments: node = m0 + wr*32 + nt*16 + l16, k = kt*32 + quad*8
    bf16x8 ax[2][4];
#pragma unroll
    for (int nt = 0; nt < 2; ++nt) {
        int node = m0 + wr * 32 + nt * 16 + l16;
        node = node < NN ? node : NN - 1;
        const unsigned short* rp = x + (size_t)node * HH + quad * 8;
#pragma unroll
        for (int kt = 0; kt < 4; ++kt)
            ax[nt][kt] = *(const bf16x8*)(rp + kt * 32);
    }
    __syncthreads();   // drains A loads + prefetch(0); covers x==root32 alias

    for (int s = 0; s < 9; ++s) {
        if (s < 8) prefetch(s + 1, (s + 1) & 1);
        const char* Bb = (const char*)&Bl[s & 1][0];

        f32x4 acc[2][4];
#pragma unroll
        for (int nt = 0; nt < 2; ++nt)
#pragma unroll
            for (int ft = 0; ft < 4; ++ft) acc[nt][ft] = (f32x4){0.f, 0.f, 0.f, 0.f};

#pragma unroll
        for (int kt = 0; kt < 4; ++kt) {
            bf16x8 bw[4];
#pragma unroll
            for (int ft = 0; ft < 4; ++ft) {
                int f = wc * 64 + ft * 16 + l16;
                bw[ft] = *(const bf16x8*)(Bb + f * 256 +
                                          (((kt * 4 + quad) ^ sw) << 4));
            }
#pragma unroll
            for (int nt = 0; nt < 2; ++nt)
#pragma unroll
                for (int ft = 0; ft < 4; ++ft)
                    acc[nt][ft] = __builtin_amdgcn_mfma_f32_16x16x32_bf16(
                        bw[ft], ax[nt][kt], acc[nt][ft], 0, 0, 0);
        }

        // transpose epilogue in two 64-row halves (h: rows h*64 .. h*64+63)
#pragma unroll
        for (int h = 0; h < 2; ++h) {
            __syncthreads();              // prev reads of Tld done; MFMA (h=0) done
            if ((wr >> 1) == h) {         // waves owning rows of this half write
#pragma unroll
                for (int nt = 0; nt < 2; ++nt) {
                    int rT = (wr & 1) * 32 + nt * 16 + l16;
#pragma unroll
                    for (int ft = 0; ft < 4; ++ft) {
                        unsigned d0, d1;
                        asm("v_cvt_pk_bf16_f32 %0, %1, %2"
                            : "=v"(d0) : "v"(acc[nt][ft][0]), "v"(acc[nt][ft][1]));
                        asm("v_cvt_pk_bf16_f32 %0, %1, %2"
                            : "=v"(d1) : "v"(acc[nt][ft][2]), "v"(acc[nt][ft][3]));
                        int slot = wc * 16 + ft * 4 + quad;     // 8B slot in row
                        *(uint2*)((char*)Tld + rT * 256 +
                                  ((slot ^ ((rT & 7) << 2)) << 3)) =
                            make_uint2(d0, d1);
                    }
                }
            }
            __syncthreads();
            // coalesced store: 8 waves x 2 passes x 4 rows = 64 rows
#pragma unroll
            for (int p = 0; p < 2; ++p) {
                int rT = p * 32 + wid * 4 + quad;
                uint4 v = *(const uint4*)((char*)Tld + rT * 256 +
                                          (((l16 * 2) ^ ((rT & 7) << 2)) << 3));
                int node = m0 + h * 64 + rT;
                if (node < NN) {
                    unsigned* dst = (s == 0) ? (root32 + (size_t)node * 64)
                                             : (y32 + ((size_t)node * 8 + (s - 1)) * 64);
                    *(uint4*)(dst + l16 * 4) = v;
                }
            }
        }
    }
}

// ---- relation-free scaled segment-sum: ONE accumulator pair per lane ----
// out[node] = relu(root[node] + b + sum_e nrm_e * y[row_e])   (wave per node)
// nrm derived per-edge from the broadcast payload (deg in bits 20..31) —
// no second ds_bpermute.
__global__ __launch_bounds__(256) void scatterAgg(
        const unsigned* __restrict__ starts, const unsigned* __restrict__ epk,
        const unsigned* __restrict__ y32, const unsigned* root32,
        const float* __restrict__ bias,
        float* __restrict__ outF, unsigned* outB) {
    int node = blockIdx.x * 4 + (threadIdx.x >> 6);
    if (node >= NN) return;
    int lane = threadIdx.x & 63;

    unsigned s0 = starts[(size_t)node * 8];
    unsigned s1 = starts[(size_t)node * 8 + 8];
    int cnt = (int)__builtin_amdgcn_readfirstlane((int)(s1 - s0));

    float ax = 0.f, ay = 0.f;
    for (int c0 = 0; c0 < cnt; c0 += 64) {
        unsigned myE = s0 + (unsigned)c0 + (unsigned)lane;
        unsigned pk = (myE < s1) ? epk[myE] : 0u;
        int cend = cnt - c0;
        if (cend > 64) cend = 64;
        for (int base = 0; base < cend; base += 8) {
            int m = cend - base;
            if (m > 8) m = 8;
            int bix = base << 2;
            unsigned pj[8], qj[8];
#pragma unroll
            for (int j = 0; j < 8; ++j)
                pj[j] = (unsigned)__builtin_amdgcn_ds_bpermute(bix + (j << 2), (int)pk);
#pragma unroll
            for (int j = 0; j < 8; ++j)
                if (j < m) qj[j] = y32[((pj[j] & 0xFFFFFu) << 6) + (unsigned)lane];
#pragma unroll
            for (int j = 0; j < 8; ++j) {
                if (j < m) {
                    float nr = __builtin_amdgcn_rcpf((float)(pj[j] >> 20));
                    float lo = __uint_as_float(qj[j] << 16);
                    float hi = __uint_as_float(qj[j] & 0xffff0000u);
                    ax += lo * nr;
                    ay += hi * nr;
                }
            }
        }
    }

    unsigned r = root32[(size_t)node * 64 + lane];
    float2 bv = ((const float2*)bias)[lane];
    float ox = ax + __uint_as_float(r << 16) + bv.x;
    float oy = ay + __uint_as_float(r & 0xffff0000u) + bv.y;
    ox = ox > 0.f ? ox : 0.f;
    oy = oy > 0.f ? oy : 0.f;
    if (outF) {
        *(float2*)(outF + (size_t)node * HH + lane * 2) = make_float2(ox, oy);
    } else {
        outB[(size_t)node * 64 + lane] =
            (unsigned)f2bf(ox) | ((unsigned)f2bf(oy) << 16);
    }
}

extern "C" void kernel_launch(void* const* d_in, const int* in_sizes, int n_in,
                              void* d_out, int out_size, void* d_ws, size_t ws_size,
                              hipStream_t stream) {
    const int* node_idx = (const int*)d_in[0];
    const int* eidx     = (const int*)d_in[1];
    const int* etype    = (const int*)d_in[2];
    const float* emb    = (const float*)d_in[3];
    const float* Wr0    = (const float*)d_in[4];
    const float* Wq0    = (const float*)d_in[5];
    const float* b0     = (const float*)d_in[6];
    const float* Wr1    = (const float*)d_in[7];
    const float* Wq1    = (const float*)d_in[8];
    const float* b1     = (const float*)d_in[9];
    const int* esrc = eidx;
    const int* edst = eidx + NE;

    char* ws = (char*)d_ws;
    size_t off = 0;
    auto alloc = [&](size_t bytes) -> void* {
        void* p = ws + off;
        off = (off + bytes + 255) & ~(size_t)255;
        return p;
    };
    // Workspace ~240.6 MB (same proven layout; y32 reuses h32's slab).
    unsigned* binCounts = (unsigned*)alloc((size_t)NBIN * 4);
    unsigned* binStarts = (unsigned*)alloc((size_t)(NBIN + 1) * 4);
    unsigned* binCursor = (unsigned*)alloc((size_t)NBIN * 4);
    unsigned* starts    = (unsigned*)alloc((size_t)NBIN * 1024 * 4);   // 3.2 MB CSR
    unsigned* epk       = (unsigned*)alloc((size_t)NE * 4);
    unsigned* xb32      = (unsigned*)alloc((size_t)NN * 64 * 4);       // x / root / out
    unsigned* y32       = (unsigned*)alloc((size_t)NN * 8 * 64 * 4);   // 204.8 MB
    unsigned short* Wt  = (unsigned short*)alloc((size_t)2 * 9 * 16384 * 2);
    unsigned* binned = y32;   // alias: y32 dead until bigGemm, binned dead after binSort
    (void)ws_size; (void)n_in; (void)in_sizes; (void)out_size;

    hipMemsetAsync(binCounts, 0, (size_t)NBIN * 4, stream);
    convertWX<<<1152 + (NN * 64 + 255) / 256, 256, 0, stream>>>(
        Wr0, Wq0, Wr1, Wq1, Wt, node_idx, emb, xb32);
    binCount<<<256, 256, 0, stream>>>(edst, binCounts);
    binScan<<<1, 1024, 0, stream>>>(binCounts, binStarts, binCursor);
    binScatter<<<128, 256, 0, stream>>>(esrc, edst, etype, binCursor, binned);
    binSort<<<NBIN, 256, 0, stream>>>(binStarts, binned, epk, starts);

    int nblk = (NN + 127) / 128;
    // layer 0: y = x@W_r, root = x@W_root (in place), then scaled segment-sum
    bigGemm<<<nblk, 512, 0, stream>>>((const unsigned short*)xb32, Wt, y32, xb32);
    scatterAgg<<<(NN + 3) / 4, 256, 0, stream>>>(starts, epk, y32, xb32, b0,
                                                 nullptr, xb32);
    // layer 1: same on relu output; final result fp32 to d_out
    bigGemm<<<nblk, 512, 0, stream>>>((const unsigned short*)xb32, Wt + 147456,
                                      y32, xb32);
    scatterAgg<<<(NN + 3) / 4, 256, 0, stream>>>(starts, epk, y32, xb32, b1,
                                                 (float*)d_out, nullptr);
}